// Round 1
// baseline (71766.687 us; speedup 1.0000x reference)
//
#include <hip/hip_runtime.h>
#include <hip/hip_cooperative_groups.h>

namespace cg = cooperative_groups;
typedef unsigned int u32;

#define DEVI __device__ __forceinline__

// ---- JAX threefry2x32 (exact) ----
DEVI void tf2x32(u32 k0, u32 k1, u32 x0, u32 x1, u32& o0, u32& o1) {
  u32 ks2 = k0 ^ k1 ^ 0x1BD11BDAu;
  x0 += k0; x1 += k1;
#define TFR(r) { x0 += x1; x1 = (x1 << (r)) | (x1 >> (32 - (r))); x1 ^= x0; }
  TFR(13) TFR(15) TFR(26) TFR(6)
  x0 += k1; x1 += ks2 + 1u;
  TFR(17) TFR(29) TFR(16) TFR(24)
  x0 += ks2; x1 += k0 + 2u;
  TFR(13) TFR(15) TFR(26) TFR(6)
  x0 += k0; x1 += k1 + 3u;
  TFR(17) TFR(29) TFR(16) TFR(24)
  x0 += k1; x1 += ks2 + 4u;
  TFR(13) TFR(15) TFR(26) TFR(6)
  x0 += ks2; x1 += k0 + 5u;
#undef TFR
  o0 = x0; o1 = x1;
}

// jax_threefry_partitionable=True path: bits(i) = o0^o1 of TF(key, hi=0, lo=i)
DEVI float jax_uniform(u32 k0, u32 k1, u32 idx) {
  u32 a, b; tf2x32(k0, k1, 0u, idx, a, b);
  u32 bits = a ^ b;
  return __uint_as_float((bits >> 9) | 0x3F800000u) - 1.0f;
}

DEVI float sigmoidf_(float x) { return 1.0f / (1.0f + expf(-x)); }

struct KArgs {
  const float* enc_key; const float* value;
  const int* labels; const int* seqlens; const int* sos;
  const float* w_emb; const float* b_emb;
  const float* w_ih0; const float* w_hh0; const float* b_ih0; const float* b_hh0;
  const float* w_ih1; const float* w_hh1; const float* b_ih1; const float* b_hh1;
  const float* w_ih2; const float* w_hh2; const float* b_ih2; const float* b_hh2;
  const float* w_fc; const float* b_fc;
  const float* w_mlp1; const float* b_mlp1;
  const float* w_mlp2; const float* b_mlp2;
  float* out; float* ws;
};

// B=64 TK=2048 TL=256 V=64 E=256 KV=128 H=512 MH=256
__global__ __launch_bounds__(1024, 4) void dec_kernel(KArgs A) {
  cg::grid_group gg = cg::this_grid();
  const int blk = blockIdx.x;
  const int tid = threadIdx.x;

  // workspace layout (floats)
  float* const LS   = A.ws;              // [256][64][64] labels_smoothed (t,b,v)
  float* const Y0   = A.ws + 1048576;    // [64][64] gumbel(sos)
  float* const XEMB = A.ws + 1052672;    // [256][256][64] emb (t,e,b)
  float* const KT   = A.ws + 5246976;    // [64][128][2048] enc_key transposed
  float* const HSb  = A.ws + 22024192;   // [3][2][512][64] h (layer,parity,j,b)
  float* const CSb  = A.ws + 22220800;   // [3][2][512][64] c
  float* const CTX  = A.ws + 22417408;   // [257][128][64] ctx (t+1,kv,b)
  float* const QA   = A.ws + 24522752;   // [256][128][64] query (t,kv,b)
  float* const ZB   = A.ws + 26619904;   // [64][2048] masked energies
  float* const MSb  = A.ws + 26750976;   // [64][4][2] chunk (max,sumexp)
  float* const WFCT = A.ws + 26751488;   // [512][128] w_fc^T

  float* const out0 = A.out;             // y_hat [64][256][64]
  float* const out1 = A.out + 1048576;   // argmax labels (as float) [64][256]
  float* const out2 = A.out + 1064960;   // labels_padded.T [64][256]
  float* const out3 = A.out + 1081344;   // labels_smoothed [64][256][64]
  float* const out4 = A.out + 2129920;   // attentions [64][2048][256]

  __shared__ float smem[8704];

  u32 KA0, KA1, KB0, KB1;                // split(key(42)) foldlike
  tf2x32(0u, 42u, 0u, 0u, KA0, KA1);     // k1
  tf2x32(0u, 42u, 0u, 1u, KB0, KB1);     // k2

  // ================= Phase P: gumbel-softmax labels / zero state / transposes
  if (blk < 65) {
    int slot = blk * 1024 + tid;
    int r = slot >> 2, q = slot & 3;     // 4 lanes per row, 16 v each
    if (r < 16448) {
      bool isY0 = (r >= 16384);
      int t = 0, b, label;
      u32 key0, key1, base;
      if (!isY0) {
        t = r >> 6; b = r & 63;
        label = A.labels[t * 64 + b];
        key0 = KA0; key1 = KA1; base = (u32)(r * 64);
      } else {
        b = r - 16384;
        label = A.sos[0];
        key0 = KB0; key1 = KB1; base = (u32)(b * 64);
      }
      float sv[16];
      float mx = -3.0e38f;
      #pragma unroll
      for (int j = 0; j < 16; ++j) {
        int v = (q << 4) + j;
        float u = jax_uniform(key0, key1, base + (u32)v);
        float inner = -logf(u + 1e-10f) + 1e-10f;
        float noise = -logf(inner);
        float s = noise + ((v == label) ? 1.0f : 0.0f);
        sv[j] = s; mx = fmaxf(mx, s);
      }
      mx = fmaxf(mx, __shfl_xor(mx, 1));
      mx = fmaxf(mx, __shfl_xor(mx, 2));
      float sum = 0.f;
      #pragma unroll
      for (int j = 0; j < 16; ++j) { sv[j] = expf(sv[j] - mx); sum += sv[j]; }
      sum += __shfl_xor(sum, 1);
      sum += __shfl_xor(sum, 2);
      float inv = 1.0f / sum;
      if (!isY0) {
        #pragma unroll
        for (int j = 0; j < 16; ++j) {
          int v = (q << 4) + j;
          float val = sv[j] * inv;
          LS[r * 64 + v] = val;
          out3[b * 16384 + t * 64 + v] = val;
        }
        if (q == 0) out2[b * 256 + t] = (float)label;
      } else {
        #pragma unroll
        for (int j = 0; j < 16; ++j) Y0[b * 64 + (q << 4) + j] = sv[j] * inv;
      }
    }
  } else if (blk < 128) {
    // zero h/c/ctx[0] (contiguous 401408 floats at HSb) + transpose w_fc
    const int total1 = 401408, total2 = 401408 + 65536;
    for (int idx = (blk - 65) * 1024 + tid; idx < total2; idx += 63 * 1024) {
      if (idx < total1) HSb[idx] = 0.f;
      else {
        int i2 = idx - total1;
        int kv = i2 >> 9, j = i2 & 511;
        WFCT[j * 128 + kv] = A.w_fc[kv * 512 + j];
      }
    }
  } else {
    // transpose enc_key -> KT[b][k][t]
    int bb = (blk - 128) >> 1, half = (blk - 128) & 1;
    const float* Kb = A.enc_key + bb * 262144;
    float* KTb = KT + bb * 262144;
    for (int tt0 = 0; tt0 < 16; ++tt0) {
      int t0 = half * 1024 + tt0 * 64;
      for (int kk0 = 0; kk0 < 2; ++kk0) {
        int k0 = kk0 * 64;
        __syncthreads();
        #pragma unroll
        for (int it = 0; it < 4; ++it) {
          int i = tid + it * 1024;
          smem[(i >> 6) * 65 + (i & 63)] = Kb[(t0 + (i >> 6)) * 128 + k0 + (i & 63)];
        }
        __syncthreads();
        #pragma unroll
        for (int it = 0; it < 4; ++it) {
          int i = tid + it * 1024;
          KTb[(k0 + (i >> 6)) * 2048 + t0 + (i & 63)] = smem[(i & 63) * 65 + (i >> 6)];
        }
      }
    }
  }
  gg.sync();

  // ================= Phase P1: embeddings XEMB[t] = emb(prev label / sos)
  {
    const int t = blk;
    const float* src = (t == 0) ? Y0 : (LS + (t - 1) * 4096);
    #pragma unroll
    for (int i = 0; i < 4; ++i) {
      int idx = tid + i * 1024;
      smem[(idx >> 6) * 65 + (idx & 63)] = src[idx];   // [b][v]
    }
    __syncthreads();
    const int sl = tid >> 6, b = tid & 63;
    float* dst = XEMB + t * 16384;
    #pragma unroll 1
    for (int e0 = 0; e0 < 16; ++e0) {
      int e = sl * 16 + e0;
      const float* we = A.w_emb + e * 64;
      float acc = A.b_emb[e];
      #pragma unroll 8
      for (int v = 0; v < 64; ++v) acc = fmaf(we[v], smem[b * 65 + v], acc);
      dst[e * 64 + b] = acc;
    }
  }
  gg.sync();

  // ================= main recurrence
  #pragma unroll 1
  for (int t = 0; t < 256; ++t) {
    const int p = t & 1;

    // ---- 3 LSTM layers: gates + update fused (8 rows/block, 16-way K split)
    #pragma unroll 1
    for (int l = 0; l < 3; ++l) {
      const int w = tid >> 6, b = tid & 63;
      const int j0 = blk * 2;
      const float *wih, *whh, *bih, *bhh;
      if (l == 0)      { wih = A.w_ih0; whh = A.w_hh0; bih = A.b_ih0; bhh = A.b_hh0; }
      else if (l == 1) { wih = A.w_ih1; whh = A.w_hh1; bih = A.b_ih1; bhh = A.b_hh1; }
      else             { wih = A.w_ih2; whh = A.w_hh2; bih = A.b_ih2; bhh = A.b_hh2; }

      float acc[8] = {0.f,0.f,0.f,0.f,0.f,0.f,0.f,0.f};
      int rowid[8];
      #pragma unroll
      for (int r = 0; r < 8; ++r) rowid[r] = (r >> 1) * 512 + j0 + (r & 1);

      auto segacc = [&](const float* xp, const float* wbase, int wstride,
                        int g0, int g1, int wcol, int kb, int ke) {
        int s0 = kb > g0 ? kb : g0;
        int s1 = ke < g1 ? ke : g1;
        int n = s1 - s0;
        if (n <= 0) return;
        const float* xq = xp + (s0 - g0) * 64 + b;
        const float* wr[8];
        #pragma unroll
        for (int r = 0; r < 8; ++r) wr[r] = wbase + rowid[r] * wstride + wcol + (s0 - g0);
        #pragma unroll 4
        for (int k = 0; k < n; ++k) {
          float xv = xq[k * 64];
          #pragma unroll
          for (int r = 0; r < 8; ++r) acc[r] = fmaf(wr[r][k], xv, acc[r]);
        }
      };

      if (l == 0) {
        int kb = w * 56, ke = kb + 56;                       // K = 256+128+512
        segacc(XEMB + t * 16384, wih, 384, 0, 256, 0, kb, ke);
        segacc(CTX + t * 8192,  wih, 384, 256, 384, 256, kb, ke);
        segacc(HSb + (0 * 2 + p) * 32768, whh, 512, 384, 896, 0, kb, ke);
      } else {
        int kb = w * 64, ke = kb + 64;                       // K = 512+512
        segacc(HSb + ((l - 1) * 2 + (p ^ 1)) * 32768, wih, 512, 0, 512, 0, kb, ke);
        segacc(HSb + (l * 2 + p) * 32768,             whh, 512, 512, 1024, 0, kb, ke);
      }
      #pragma unroll
      for (int r = 0; r < 8; ++r) smem[w * 512 + r * 64 + b] = acc[r];
      __syncthreads();
      if (tid < 128) {
        int jj = tid >> 6, bb = tid & 63;
        int j = j0 + jj;
        float g4[4];
        #pragma unroll
        for (int g = 0; g < 4; ++g) {
          float s = 0.f;
          #pragma unroll
          for (int w2 = 0; w2 < 16; ++w2) s += smem[w2 * 512 + (g * 2 + jj) * 64 + bb];
          int row = g * 512 + j;
          g4[g] = s + bih[row] + bhh[row];
        }
        float cprev = CSb[(l * 2 + p) * 32768 + j * 64 + bb];
        float c2 = sigmoidf_(g4[1]) * cprev + sigmoidf_(g4[0]) * tanhf(g4[2]);
        CSb[(l * 2 + (p ^ 1)) * 32768 + j * 64 + bb] = c2;
        HSb[(l * 2 + (p ^ 1)) * 32768 + j * 64 + bb] = sigmoidf_(g4[3]) * tanhf(c2);
      }
      gg.sync();
    }

    // ---- A3: query (redundant per chunk), energy, chunk softmax stats
    {
      const int b = blk >> 2, ch = blk & 3;
      const float* H2 = HSb + (4 + (p ^ 1)) * 32768;
      {
        int kv = tid & 127, jq = tid >> 7;
        float pa = 0.f;
        #pragma unroll 8
        for (int jl = 0; jl < 64; ++jl) {
          int j = jq * 64 + jl;
          pa = fmaf(WFCT[j * 128 + kv], H2[j * 64 + b], pa);
        }
        smem[128 + jq * 128 + kv] = pa;
      }
      __syncthreads();
      if (tid < 128) {
        float qv = A.b_fc[tid];
        #pragma unroll
        for (int jq = 0; jq < 8; ++jq) qv += smem[128 + jq * 128 + tid];
        smem[tid] = qv;
        if (ch == 0) QA[t * 8192 + tid * 64 + b] = qv;
      }
      __syncthreads();
      float z = 0.f;
      if (tid < 512) {
        int myt = ch * 512 + tid;
        const float* kp = KT + b * 262144 + myt;
        float e = 0.f;
        #pragma unroll 8
        for (int k = 0; k < 128; ++k) e = fmaf(kp[k * 2048], smem[k], e);
        z = (myt < A.seqlens[b]) ? e : 0.0f;    // energy * mask
        ZB[b * 2048 + myt] = z;
        float wm = z;
        #pragma unroll
        for (int d = 1; d < 64; d <<= 1) wm = fmaxf(wm, __shfl_xor(wm, d));
        if ((tid & 63) == 0) smem[1152 + (tid >> 6)] = wm;
      }
      __syncthreads();
      float mc = smem[1152];
      #pragma unroll
      for (int i = 1; i < 8; ++i) mc = fmaxf(mc, smem[1152 + i]);
      if (tid < 512) {
        float es = expf(z - mc);
        #pragma unroll
        for (int d = 1; d < 64; d <<= 1) es += __shfl_xor(es, d);
        if ((tid & 63) == 0) smem[1160 + (tid >> 6)] = es;
      }
      __syncthreads();
      if (tid == 0) {
        float sc = 0.f;
        #pragma unroll
        for (int i = 0; i < 8; ++i) sc += smem[1160 + i];
        MSb[(b * 4 + ch) * 2] = mc;
        MSb[(b * 4 + ch) * 2 + 1] = sc;
      }
    }
    gg.sync();

    // ---- A4: finalize softmax, write attentions, ctx2 = attn @ value
    {
      const int b = blk >> 2, kq = blk & 3;
      float m = MSb[b * 8];
      #pragma unroll
      for (int c = 1; c < 4; ++c) m = fmaxf(m, MSb[b * 8 + c * 2]);
      float Z = 0.f;
      #pragma unroll
      for (int c = 0; c < 4; ++c) Z += MSb[b * 8 + c * 2 + 1] * expf(MSb[b * 8 + c * 2] - m);
      float invZ = 1.0f / Z;
      #pragma unroll
      for (int i = 0; i < 2; ++i) {
        int tt = tid + i * 1024;
        float a = expf(ZB[b * 2048 + tt] - m) * invZ;
        smem[tt] = a;
        if (kq == 0) out4[b * 524288 + tt * 256 + t] = a;
      }
      __syncthreads();
      {
        int kv = tid & 31, tg = tid >> 5;
        const float* vp = A.value + b * 262144 + kq * 32 + kv;
        float acc2 = 0.f;
        #pragma unroll 4
        for (int i = 0; i < 64; ++i) {
          int tt = tg * 64 + i;
          acc2 = fmaf(smem[tt], vp[tt * 128], acc2);
        }
        smem[2048 + tg * 32 + kv] = acc2;
      }
      __syncthreads();
      if (tid < 32) {
        float c2 = 0.f;
        #pragma unroll
        for (int g = 0; g < 32; ++g) c2 += smem[2048 + g * 32 + tid];
        CTX[(t + 1) * 8192 + (kq * 32 + tid) * 64 + b] = c2;
      }
    }
    gg.sync();
  }

  // ================= Epilogue: batched MLP head + argmax (block = one t)
  {
    const int t = blk;
    const int sl = tid >> 6, b = tid & 63;
    float acc1[16];
    #pragma unroll
    for (int i = 0; i < 16; ++i) acc1[i] = 0.f;
    #pragma unroll 1
    for (int h = 0; h < 2; ++h) {
      __syncthreads();
      const float* src = (h == 0) ? (QA + t * 8192) : (CTX + (t + 1) * 8192);
      #pragma unroll
      for (int i = 0; i < 8; ++i) {
        int idx = tid + i * 1024;
        smem[(idx >> 6) * 65 + (idx & 63)] = src[idx];
      }
      __syncthreads();
      const float* w1 = A.w_mlp1 + (sl * 16) * 256 + h * 128;
      #pragma unroll 2
      for (int k = 0; k < 128; ++k) {
        float xv = smem[k * 65 + b];
        #pragma unroll
        for (int m2 = 0; m2 < 16; ++m2) acc1[m2] = fmaf(w1[m2 * 256 + k], xv, acc1[m2]);
      }
    }
    #pragma unroll
    for (int m2 = 0; m2 < 16; ++m2) {
      float v2 = acc1[m2] + A.b_mlp1[sl * 16 + m2];
      acc1[m2] = (v2 >= 0.f) ? v2 : 0.9f * v2;          // LeakyReLU(0.9)
    }
    float y[4] = {0.f, 0.f, 0.f, 0.f};
    #pragma unroll 1
    for (int h = 0; h < 2; ++h) {
      __syncthreads();
      if ((sl >> 3) == h) {
        int base = (sl & 7) * 16;
        #pragma unroll
        for (int m2 = 0; m2 < 16; ++m2) smem[(base + m2) * 65 + b] = acc1[m2];
      }
      __syncthreads();
      const float* w2 = A.w_mlp2 + (sl * 4) * 256 + h * 128;
      #pragma unroll 2
      for (int k = 0; k < 128; ++k) {
        float xv = smem[k * 65 + b];
        #pragma unroll
        for (int m2 = 0; m2 < 4; ++m2) y[m2] = fmaf(w2[m2 * 256 + k], xv, y[m2]);
      }
    }
    #pragma unroll
    for (int m2 = 0; m2 < 4; ++m2) y[m2] += A.b_mlp2[sl * 4 + m2];
    *(float4*)(out0 + b * 16384 + t * 64 + sl * 4) = make_float4(y[0], y[1], y[2], y[3]);
    __syncthreads();
    #pragma unroll
    for (int m2 = 0; m2 < 4; ++m2) smem[(sl * 4 + m2) * 65 + b] = y[m2];
    __syncthreads();
    if (tid < 64) {
      float best = smem[tid];
      int bi = 0;
      #pragma unroll 1
      for (int v = 1; v < 64; ++v) {
        float val = smem[v * 65 + tid];
        if (val > best) { best = val; bi = v; }   // first-occurrence argmax
      }
      out1[tid * 256 + t] = (float)bi;
    }
  }
}

extern "C" void kernel_launch(void* const* d_in, const int* in_sizes, int n_in,
                              void* d_out, int out_size, void* d_ws, size_t ws_size,
                              hipStream_t stream) {
  if (ws_size < (size_t)26817024 * 4) return;  // need ~107 MB of scratch
  KArgs a;
  a.enc_key = (const float*)d_in[0];
  a.value   = (const float*)d_in[1];
  a.labels  = (const int*)d_in[2];
  a.seqlens = (const int*)d_in[3];
  a.sos     = (const int*)d_in[4];
  a.w_emb  = (const float*)d_in[6];  a.b_emb  = (const float*)d_in[7];
  a.w_ih0  = (const float*)d_in[8];  a.w_hh0  = (const float*)d_in[9];
  a.b_ih0  = (const float*)d_in[10]; a.b_hh0  = (const float*)d_in[11];
  a.w_ih1  = (const float*)d_in[12]; a.w_hh1  = (const float*)d_in[13];
  a.b_ih1  = (const float*)d_in[14]; a.b_hh1  = (const float*)d_in[15];
  a.w_ih2  = (const float*)d_in[16]; a.w_hh2  = (const float*)d_in[17];
  a.b_ih2  = (const float*)d_in[18]; a.b_hh2  = (const float*)d_in[19];
  a.w_fc   = (const float*)d_in[20]; a.b_fc   = (const float*)d_in[21];
  a.w_mlp1 = (const float*)d_in[22]; a.b_mlp1 = (const float*)d_in[23];
  a.w_mlp2 = (const float*)d_in[24]; a.b_mlp2 = (const float*)d_in[25];
  a.out = (float*)d_out;
  a.ws  = (float*)d_ws;
  void* args[] = { (void*)&a };
  hipLaunchCooperativeKernel(reinterpret_cast<void*>(dec_kernel),
                             dim3(256), dim3(1024), args, 0, stream);
}

// Round 2
// 40725.671 us; speedup vs baseline: 1.7622x; 1.7622x over previous
//
#include <hip/hip_runtime.h>

typedef unsigned int u32;
#define DEVI __device__ __forceinline__

// ---- JAX threefry2x32 (exact) ----
DEVI void tf2x32(u32 k0, u32 k1, u32 x0, u32 x1, u32& o0, u32& o1) {
  u32 ks2 = k0 ^ k1 ^ 0x1BD11BDAu;
  x0 += k0; x1 += k1;
#define TFR(r) { x0 += x1; x1 = (x1 << (r)) | (x1 >> (32 - (r))); x1 ^= x0; }
  TFR(13) TFR(15) TFR(26) TFR(6)
  x0 += k1; x1 += ks2 + 1u;
  TFR(17) TFR(29) TFR(16) TFR(24)
  x0 += ks2; x1 += k0 + 2u;
  TFR(13) TFR(15) TFR(26) TFR(6)
  x0 += k0; x1 += k1 + 3u;
  TFR(17) TFR(29) TFR(16) TFR(24)
  x0 += k1; x1 += ks2 + 4u;
  TFR(13) TFR(15) TFR(26) TFR(6)
  x0 += ks2; x1 += k0 + 5u;
#undef TFR
  o0 = x0; o1 = x1;
}

DEVI float jax_uniform(u32 k0, u32 k1, u32 idx) {
  u32 a, b; tf2x32(k0, k1, 0u, idx, a, b);
  u32 bits = a ^ b;
  return __uint_as_float((bits >> 9) | 0x3F800000u) - 1.0f;
}

DEVI float sigmoidf_(float x) { return 1.0f / (1.0f + expf(-x)); }

struct KArgs {
  const float* enc_key; const float* value;
  const int* labels; const int* seqlens; const int* sos;
  const float* w_emb; const float* b_emb;
  const float* w_ih0; const float* w_hh0; const float* b_ih0; const float* b_hh0;
  const float* w_ih1; const float* w_hh1; const float* b_ih1; const float* b_hh1;
  const float* w_ih2; const float* w_hh2; const float* b_ih2; const float* b_hh2;
  const float* w_fc; const float* b_fc;
  const float* w_mlp1; const float* b_mlp1;
  const float* w_mlp2; const float* b_mlp2;
  float* out; float* ws;
};

// custom two-level grid barrier: 16 groups x 16 blocks, monotonic counters.
// bar[g*32] group counters, bar[512] top counter, bar[544] release epoch.
DEVI void gridbar(int* bar, int& ep) {
  __syncthreads();
  if (threadIdx.x == 0) {
    __threadfence();   // release: make this block's writes visible at coherence point
    int g = (int)(blockIdx.x & 15);
    int old = __hip_atomic_fetch_add(bar + g * 32, 1, __ATOMIC_RELAXED, __HIP_MEMORY_SCOPE_AGENT);
    if (old == ep * 16 - 1) {
      int o2 = __hip_atomic_fetch_add(bar + 512, 1, __ATOMIC_RELAXED, __HIP_MEMORY_SCOPE_AGENT);
      if (o2 == ep * 16 - 1)
        __hip_atomic_store(bar + 544, ep, __ATOMIC_RELAXED, __HIP_MEMORY_SCOPE_AGENT);
    }
    while (__hip_atomic_load(bar + 544, __ATOMIC_RELAXED, __HIP_MEMORY_SCOPE_AGENT) < ep)
      __builtin_amdgcn_s_sleep(1);
    __threadfence();   // acquire: invalidate stale cached data
  }
  __syncthreads();
  ++ep;
}

__global__ void bar_init_kernel(int* bar) {
  bar[threadIdx.x] = 0;   // 1024 ints cover the whole barrier region
}

// B=64 TK=2048 TL=256 V=64 E=256 KV=128 H=512 MH=256
__global__ __launch_bounds__(1024, 4) void dec_kernel(KArgs A) {
  const int blk = blockIdx.x;
  const int tid = threadIdx.x;

  // workspace layout (floats)
  float* const LS   = A.ws;              // [256][64][64] labels_smoothed (t,b,v)
  float* const Y0   = A.ws + 1048576;    // [64][64] gumbel(sos)
  float* const XEMB = A.ws + 1052672;    // [256][256][64] emb (t,e,b)
  float4* const KT4 = (float4*)(A.ws + 5246976); // [64][32][2048] float4: K packed k4-major
  float* const HSb  = A.ws + 22024192;   // [3][2][512][64] h (layer,parity,j,b)
  float* const CSb  = A.ws + 22220800;   // [3][2][512][64] c
  float* const CTX  = A.ws + 22417408;   // [257][128][64] ctx (t+1,kv,b)
  float* const QA   = A.ws + 24522752;   // [256][128][64] query (t,kv,b)
  int*   const bar  = (int*)(A.ws + 26619904); // barrier state (old ZB region)
  float* const WFCT = A.ws + 26751488;   // [512][128] w_fc^T

  float* const out0 = A.out;             // y_hat [64][256][64]
  float* const out1 = A.out + 1048576;   // argmax labels (as float) [64][256]
  float* const out2 = A.out + 1064960;   // labels_padded.T [64][256]
  float* const out3 = A.out + 1081344;   // labels_smoothed [64][256][64]
  float* const out4 = A.out + 2129920;   // attentions [64][2048][256]

  __shared__ float smem[8704];
  int ep = 1;

  u32 KA0, KA1, KB0, KB1;                // split(key(42)) foldlike
  tf2x32(0u, 42u, 0u, 0u, KA0, KA1);     // k1
  tf2x32(0u, 42u, 0u, 1u, KB0, KB1);     // k2

  // ================= Phase P: gumbel-softmax labels / zero state / K packing
  if (blk < 65) {
    int slot = blk * 1024 + tid;
    int r = slot >> 2, q = slot & 3;     // 4 lanes per row, 16 v each
    if (r < 16448) {
      bool isY0 = (r >= 16384);
      int t = 0, b, label;
      u32 key0, key1, base;
      if (!isY0) {
        t = r >> 6; b = r & 63;
        label = A.labels[t * 64 + b];
        key0 = KA0; key1 = KA1; base = (u32)(r * 64);
      } else {
        b = r - 16384;
        label = A.sos[0];
        key0 = KB0; key1 = KB1; base = (u32)(b * 64);
      }
      float sv[16];
      float mx = -3.0e38f;
      #pragma unroll
      for (int j = 0; j < 16; ++j) {
        int v = (q << 4) + j;
        float u = jax_uniform(key0, key1, base + (u32)v);
        float inner = -logf(u + 1e-10f) + 1e-10f;
        float noise = -logf(inner);
        float s = noise + ((v == label) ? 1.0f : 0.0f);
        sv[j] = s; mx = fmaxf(mx, s);
      }
      mx = fmaxf(mx, __shfl_xor(mx, 1));
      mx = fmaxf(mx, __shfl_xor(mx, 2));
      float sum = 0.f;
      #pragma unroll
      for (int j = 0; j < 16; ++j) { sv[j] = expf(sv[j] - mx); sum += sv[j]; }
      sum += __shfl_xor(sum, 1);
      sum += __shfl_xor(sum, 2);
      float inv = 1.0f / sum;
      if (!isY0) {
        #pragma unroll
        for (int j = 0; j < 16; ++j) {
          int v = (q << 4) + j;
          float val = sv[j] * inv;
          LS[r * 64 + v] = val;
          out3[b * 16384 + t * 64 + v] = val;
        }
        if (q == 0) out2[b * 256 + t] = (float)label;
      } else {
        #pragma unroll
        for (int j = 0; j < 16; ++j) Y0[b * 64 + (q << 4) + j] = sv[j] * inv;
      }
    }
  } else if (blk < 128) {
    // zero h/c/ctx[0] (contiguous 401408 floats at HSb) + transpose w_fc
    const int total1 = 401408, total2 = 401408 + 65536;
    for (int idx = (blk - 65) * 1024 + tid; idx < total2; idx += 63 * 1024) {
      if (idx < total1) HSb[idx] = 0.f;
      else {
        int i2 = idx - total1;
        int kv = i2 >> 9, j = i2 & 511;
        WFCT[j * 128 + kv] = A.w_fc[kv * 512 + j];
      }
    }
  } else {
    // pack enc_key -> KT4[b][k4][t] = float4(K[b][t][4k4..4k4+3])
    int bb = (blk - 128) >> 1, half = (blk - 128) & 1;
    const float* Kb = A.enc_key + bb * 262144;
    float4* KTb = KT4 + bb * 65536;
    for (int tile = 0; tile < 16; ++tile) {
      int t0 = half * 1024 + tile * 64;
      __syncthreads();
      #pragma unroll
      for (int it = 0; it < 8; ++it) {
        int i = tid + it * 1024;
        int tt = i >> 7, k = i & 127;
        smem[tt * 129 + k] = Kb[(t0 + tt) * 128 + k];
      }
      __syncthreads();
      #pragma unroll
      for (int w = 0; w < 2; ++w) {
        int lin = tid + w * 1024;
        int k4 = lin >> 6, tl = lin & 63;
        float4 v = make_float4(smem[tl * 129 + k4 * 4],     smem[tl * 129 + k4 * 4 + 1],
                               smem[tl * 129 + k4 * 4 + 2], smem[tl * 129 + k4 * 4 + 3]);
        KTb[k4 * 2048 + t0 + tl] = v;
      }
    }
  }
  gridbar(bar, ep);

  // ================= Phase P1: embeddings XEMB[t] = emb(prev label / sos)
  {
    const int t = blk;
    const float* src = (t == 0) ? Y0 : (LS + (t - 1) * 4096);
    #pragma unroll
    for (int i = 0; i < 4; ++i) {
      int idx = tid + i * 1024;
      smem[(idx >> 6) * 65 + (idx & 63)] = src[idx];   // [b][v]
    }
    __syncthreads();
    const int sl = tid >> 6, b = tid & 63;
    float* dst = XEMB + t * 16384;
    #pragma unroll 1
    for (int e0 = 0; e0 < 16; ++e0) {
      int e = sl * 16 + e0;
      const float* we = A.w_emb + e * 64;
      float acc = A.b_emb[e];
      #pragma unroll 8
      for (int v = 0; v < 64; ++v) acc = fmaf(we[v], smem[b * 65 + v], acc);
      dst[e * 64 + b] = acc;
    }
  }
  gridbar(bar, ep);

  const int len_b = (blk < 64) ? A.seqlens[blk] : 0;

  // ================= main recurrence: 4 phases (barriers) per step
  #pragma unroll 1
  for (int t = 0; t < 256; ++t) {
    const int p = t & 1;

    // ---- 3 LSTM layers: gates + update fused (8 rows/block, 16-way K split)
    #pragma unroll 1
    for (int l = 0; l < 3; ++l) {
      const int w = tid >> 6, b = tid & 63;
      const int j0 = blk * 2;
      const float *wih, *whh, *bih, *bhh;
      if (l == 0)      { wih = A.w_ih0; whh = A.w_hh0; bih = A.b_ih0; bhh = A.b_hh0; }
      else if (l == 1) { wih = A.w_ih1; whh = A.w_hh1; bih = A.b_ih1; bhh = A.b_hh1; }
      else             { wih = A.w_ih2; whh = A.w_hh2; bih = A.b_ih2; bhh = A.b_hh2; }

      float acc[8] = {0.f,0.f,0.f,0.f,0.f,0.f,0.f,0.f};
      int rowid[8];
      #pragma unroll
      for (int r = 0; r < 8; ++r) rowid[r] = (r >> 1) * 512 + j0 + (r & 1);

      auto segacc = [&](const float* xp, const float* wbase, int wstride,
                        int g0, int g1, int wcol, int kb, int ke) {
        int s0 = kb > g0 ? kb : g0;
        int s1 = ke < g1 ? ke : g1;
        int n4 = (s1 - s0) >> 2;
        if (s1 - s0 <= 0) return;
        const float* xq = xp + (s0 - g0) * 64 + b;
        const float4* wr[8];
        #pragma unroll
        for (int r = 0; r < 8; ++r)
          wr[r] = (const float4*)(wbase + rowid[r] * wstride + wcol + (s0 - g0));
        #pragma unroll 2
        for (int k4 = 0; k4 < n4; ++k4) {
          float x0 = xq[(k4 * 4 + 0) * 64];
          float x1 = xq[(k4 * 4 + 1) * 64];
          float x2 = xq[(k4 * 4 + 2) * 64];
          float x3 = xq[(k4 * 4 + 3) * 64];
          #pragma unroll
          for (int r = 0; r < 8; ++r) {
            float4 w4 = wr[r][k4];
            acc[r] = fmaf(w4.x, x0, acc[r]);
            acc[r] = fmaf(w4.y, x1, acc[r]);
            acc[r] = fmaf(w4.z, x2, acc[r]);
            acc[r] = fmaf(w4.w, x3, acc[r]);
          }
        }
      };

      if (l == 0) {
        int kb = w * 56, ke = kb + 56;                       // K = 256+128+512
        segacc(XEMB + t * 16384, wih, 384, 0, 256, 0, kb, ke);
        segacc(CTX + t * 8192,  wih, 384, 256, 384, 256, kb, ke);
        segacc(HSb + (0 * 2 + p) * 32768, whh, 512, 384, 896, 0, kb, ke);
      } else {
        int kb = w * 64, ke = kb + 64;                       // K = 512+512
        segacc(HSb + ((l - 1) * 2 + (p ^ 1)) * 32768, wih, 512, 0, 512, 0, kb, ke);
        segacc(HSb + (l * 2 + p) * 32768,             whh, 512, 512, 1024, 0, kb, ke);
      }
      #pragma unroll
      for (int r = 0; r < 8; ++r) smem[w * 512 + r * 64 + b] = acc[r];
      __syncthreads();
      if (tid < 128) {
        int jj = tid >> 6, bb = tid & 63;
        int j = j0 + jj;
        float g4[4];
        #pragma unroll
        for (int g = 0; g < 4; ++g) {
          float s = 0.f;
          #pragma unroll
          for (int w2 = 0; w2 < 16; ++w2) s += smem[w2 * 512 + (g * 2 + jj) * 64 + bb];
          int row = g * 512 + j;
          g4[g] = s + bih[row] + bhh[row];
        }
        float cprev = CSb[(l * 2 + p) * 32768 + j * 64 + bb];
        float c2 = sigmoidf_(g4[1]) * cprev + sigmoidf_(g4[0]) * tanhf(g4[2]);
        CSb[(l * 2 + (p ^ 1)) * 32768 + j * 64 + bb] = c2;
        HSb[(l * 2 + (p ^ 1)) * 32768 + j * 64 + bb] = sigmoidf_(g4[3]) * tanhf(c2);
      }
      gridbar(bar, ep);
    }

    // ---- ATTN: one block per batch, fully fused (query/energy/softmax/ctx)
    if (blk < 64) {
      const int b = blk;
      const float* H2 = HSb + (4 + (p ^ 1)) * 32768;
      const int kv = tid & 127, jq = tid >> 7;
      {
        const float* wf = WFCT + (jq * 64) * 128 + kv;
        const float* h2 = H2 + (jq * 64) * 64 + b;
        float pa = 0.f;
        #pragma unroll 8
        for (int jl = 0; jl < 64; ++jl)
          pa = fmaf(wf[jl * 128], h2[jl * 64], pa);
        smem[1024 + jq * 128 + kv] = pa;
      }
      __syncthreads();
      if (tid < 128) {
        float qv = A.b_fc[tid];
        #pragma unroll
        for (int g2 = 0; g2 < 8; ++g2) qv += smem[1024 + g2 * 128 + tid];
        smem[tid] = qv;
        QA[t * 8192 + tid * 64 + b] = qv;
      }
      __syncthreads();
      // energy for 2 columns: myt = tid and tid+1024
      const float4* kp = KT4 + b * 65536 + tid;
      float e0 = 0.f, e1 = 0.f;
      #pragma unroll 8
      for (int k4 = 0; k4 < 32; ++k4) {
        float4 a4 = kp[k4 * 2048];
        float4 b4 = kp[k4 * 2048 + 1024];
        float q0 = smem[k4 * 4], q1 = smem[k4 * 4 + 1];
        float q2 = smem[k4 * 4 + 2], q3 = smem[k4 * 4 + 3];
        e0 = fmaf(a4.x, q0, fmaf(a4.y, q1, fmaf(a4.z, q2, fmaf(a4.w, q3, e0))));
        e1 = fmaf(b4.x, q0, fmaf(b4.y, q1, fmaf(b4.z, q2, fmaf(b4.w, q3, e1))));
      }
      float z0 = (tid < len_b) ? e0 : 0.0f;          // energy * mask
      float z1 = (tid + 1024 < len_b) ? e1 : 0.0f;
      // block softmax over 2048
      float m = fmaxf(z0, z1);
      #pragma unroll
      for (int d = 1; d < 64; d <<= 1) m = fmaxf(m, __shfl_xor(m, d));
      if ((tid & 63) == 0) smem[2048 + (tid >> 6)] = m;
      __syncthreads();
      m = smem[2048];
      #pragma unroll
      for (int i2 = 1; i2 < 16; ++i2) m = fmaxf(m, smem[2048 + i2]);
      float s0 = expf(z0 - m), s1 = expf(z1 - m);
      float s = s0 + s1;
      #pragma unroll
      for (int d = 1; d < 64; d <<= 1) s += __shfl_xor(s, d);
      if ((tid & 63) == 0) smem[2080 + (tid >> 6)] = s;
      __syncthreads();
      float Z = 0.f;
      #pragma unroll
      for (int i2 = 0; i2 < 16; ++i2) Z += smem[2080 + i2];
      float invZ = 1.0f / Z;
      float a0 = s0 * invZ, a1 = s1 * invZ;
      smem[2176 + tid] = a0;
      smem[2176 + 1024 + tid] = a1;
      out4[b * 524288 + tid * 256 + t] = a0;
      out4[b * 524288 + (tid + 1024) * 256 + t] = a1;
      __syncthreads();
      // ctx2 = attn @ value (float2 over kv, 16 t-groups)
      {
        const int kv2 = (tid & 63) * 2, tg = tid >> 6;
        const float2* vp = (const float2*)(A.value + b * 262144 + kv2);
        float cx = 0.f, cy = 0.f;
        #pragma unroll 8
        for (int i2 = 0; i2 < 128; ++i2) {
          int tt = tg * 128 + i2;
          float2 v2 = vp[tt * 64];
          float av = smem[2176 + tt];
          cx = fmaf(v2.x, av, cx);
          cy = fmaf(v2.y, av, cy);
        }
        smem[4224 + tg * 128 + kv2]     = cx;
        smem[4224 + tg * 128 + kv2 + 1] = cy;
      }
      __syncthreads();
      if (tid < 128) {
        float c2 = 0.f;
        #pragma unroll
        for (int g2 = 0; g2 < 16; ++g2) c2 += smem[4224 + g2 * 128 + tid];
        CTX[(t + 1) * 8192 + tid * 64 + b] = c2;
      }
    }
    gridbar(bar, ep);
  }

  // ================= Epilogue: batched MLP head + argmax (block = one t)
  {
    const int t = blk;
    const int sl = tid >> 6, b = tid & 63;
    float acc1[16];
    #pragma unroll
    for (int i = 0; i < 16; ++i) acc1[i] = 0.f;
    #pragma unroll 1
    for (int h = 0; h < 2; ++h) {
      __syncthreads();
      const float* src = (h == 0) ? (QA + t * 8192) : (CTX + (t + 1) * 8192);
      #pragma unroll
      for (int i = 0; i < 8; ++i) {
        int idx = tid + i * 1024;
        smem[(idx >> 6) * 65 + (idx & 63)] = src[idx];
      }
      __syncthreads();
      const float* w1 = A.w_mlp1 + (sl * 16) * 256 + h * 128;
      #pragma unroll 2
      for (int k = 0; k < 128; ++k) {
        float xv = smem[k * 65 + b];
        #pragma unroll
        for (int m2 = 0; m2 < 16; ++m2) acc1[m2] = fmaf(w1[m2 * 256 + k], xv, acc1[m2]);
      }
    }
    #pragma unroll
    for (int m2 = 0; m2 < 16; ++m2) {
      float v2 = acc1[m2] + A.b_mlp1[sl * 16 + m2];
      acc1[m2] = (v2 >= 0.f) ? v2 : 0.9f * v2;          // LeakyReLU(0.9)
    }
    float y[4] = {0.f, 0.f, 0.f, 0.f};
    #pragma unroll 1
    for (int h = 0; h < 2; ++h) {
      __syncthreads();
      if ((sl >> 3) == h) {
        int base = (sl & 7) * 16;
        #pragma unroll
        for (int m2 = 0; m2 < 16; ++m2) smem[(base + m2) * 65 + b] = acc1[m2];
      }
      __syncthreads();
      const float* w2 = A.w_mlp2 + (sl * 4) * 256 + h * 128;
      #pragma unroll 2
      for (int k = 0; k < 128; ++k) {
        float xv = smem[k * 65 + b];
        #pragma unroll
        for (int m2 = 0; m2 < 4; ++m2) y[m2] = fmaf(w2[m2 * 256 + k], xv, y[m2]);
      }
    }
    #pragma unroll
    for (int m2 = 0; m2 < 4; ++m2) y[m2] += A.b_mlp2[sl * 4 + m2];
    *(float4*)(out0 + b * 16384 + t * 64 + sl * 4) = make_float4(y[0], y[1], y[2], y[3]);
    __syncthreads();
    #pragma unroll
    for (int m2 = 0; m2 < 4; ++m2) smem[(sl * 4 + m2) * 65 + b] = y[m2];
    __syncthreads();
    if (tid < 64) {
      float best = smem[tid];
      int bi = 0;
      #pragma unroll 1
      for (int v = 1; v < 64; ++v) {
        float val = smem[v * 65 + tid];
        if (val > best) { best = val; bi = v; }   // first-occurrence argmax
      }
      out1[tid * 256 + t] = (float)bi;
    }
  }
}

extern "C" void kernel_launch(void* const* d_in, const int* in_sizes, int n_in,
                              void* d_out, int out_size, void* d_ws, size_t ws_size,
                              hipStream_t stream) {
  if (ws_size < (size_t)26817024 * 4) return;  // need ~107 MB of scratch
  KArgs a;
  a.enc_key = (const float*)d_in[0];
  a.value   = (const float*)d_in[1];
  a.labels  = (const int*)d_in[2];
  a.seqlens = (const int*)d_in[3];
  a.sos     = (const int*)d_in[4];
  a.w_emb  = (const float*)d_in[6];  a.b_emb  = (const float*)d_in[7];
  a.w_ih0  = (const float*)d_in[8];  a.w_hh0  = (const float*)d_in[9];
  a.b_ih0  = (const float*)d_in[10]; a.b_hh0  = (const float*)d_in[11];
  a.w_ih1  = (const float*)d_in[12]; a.w_hh1  = (const float*)d_in[13];
  a.b_ih1  = (const float*)d_in[14]; a.b_hh1  = (const float*)d_in[15];
  a.w_ih2  = (const float*)d_in[16]; a.w_hh2  = (const float*)d_in[17];
  a.b_ih2  = (const float*)d_in[18]; a.b_hh2  = (const float*)d_in[19];
  a.w_fc   = (const float*)d_in[20]; a.b_fc   = (const float*)d_in[21];
  a.w_mlp1 = (const float*)d_in[22]; a.b_mlp1 = (const float*)d_in[23];
  a.w_mlp2 = (const float*)d_in[24]; a.b_mlp2 = (const float*)d_in[25];
  a.out = (float*)d_out;
  a.ws  = (float*)d_ws;

  int* bar = (int*)((float*)d_ws + 26619904);
  hipLaunchKernelGGL(bar_init_kernel, dim3(1), dim3(1024), 0, stream, bar);

  void* args[] = { (void*)&a };
  hipLaunchCooperativeKernel(reinterpret_cast<void*>(dec_kernel),
                             dim3(256), dim3(1024), args, 0, stream);
}

// Round 3
// 38951.837 us; speedup vs baseline: 1.8424x; 1.0455x over previous
//
#include <hip/hip_runtime.h>

typedef unsigned int u32;
#define DEVI __device__ __forceinline__

// ---- JAX threefry2x32 (exact) ----
DEVI void tf2x32(u32 k0, u32 k1, u32 x0, u32 x1, u32& o0, u32& o1) {
  u32 ks2 = k0 ^ k1 ^ 0x1BD11BDAu;
  x0 += k0; x1 += k1;
#define TFR(r) { x0 += x1; x1 = (x1 << (r)) | (x1 >> (32 - (r))); x1 ^= x0; }
  TFR(13) TFR(15) TFR(26) TFR(6)
  x0 += k1; x1 += ks2 + 1u;
  TFR(17) TFR(29) TFR(16) TFR(24)
  x0 += ks2; x1 += k0 + 2u;
  TFR(13) TFR(15) TFR(26) TFR(6)
  x0 += k0; x1 += k1 + 3u;
  TFR(17) TFR(29) TFR(16) TFR(24)
  x0 += k1; x1 += ks2 + 4u;
  TFR(13) TFR(15) TFR(26) TFR(6)
  x0 += ks2; x1 += k0 + 5u;
#undef TFR
  o0 = x0; o1 = x1;
}

DEVI float jax_uniform(u32 k0, u32 k1, u32 idx) {
  u32 a, b; tf2x32(k0, k1, 0u, idx, a, b);
  u32 bits = a ^ b;
  return __uint_as_float((bits >> 9) | 0x3F800000u) - 1.0f;
}

DEVI float sigmoidf_(float x) { return 1.0f / (1.0f + expf(-x)); }

// async global->LDS, 16B per lane (dest = wave-uniform base + lane*16)
typedef const __attribute__((address_space(1))) u32* gas1;
typedef __attribute__((address_space(3))) u32* las3;
DEVI void gl16(const float* g, float* l) {
  __builtin_amdgcn_global_load_lds((gas1)g, (las3)l, 16, 0, 0);
}
#define WAITV(N) asm volatile("s_waitcnt vmcnt(" #N ")" ::: "memory")

struct KArgs {
  const float* enc_key; const float* value;
  const int* labels; const int* seqlens; const int* sos;
  const float* w_emb; const float* b_emb;
  const float* w_ih0; const float* w_hh0; const float* b_ih0; const float* b_hh0;
  const float* w_ih1; const float* w_hh1; const float* b_ih1; const float* b_hh1;
  const float* w_ih2; const float* w_hh2; const float* b_ih2; const float* b_hh2;
  const float* w_fc; const float* b_fc;
  const float* w_mlp1; const float* b_mlp1;
  const float* w_mlp2; const float* b_mlp2;
  float* out; float* ws;
};

// ws offsets (floats)
#define OF_LS     0
#define OF_Y0     1048576
#define OF_XEMB   1052672
#define OF_HSB    5246976
#define OF_CSB    5443584
#define OF_CTXP   5640192   // [257][4][128][64]
#define OF_MS     14061568  // [257][4][2][64]
#define OF_QA     14193152  // [256][128][64]
#define OF_WPK    16290304  // packed weights
#define OF_WFCT   22319616  // [512][128]
#define OF_BAR    22385152
#define WS_TOTAL  22386176
#define WP1 1835008
#define WP2 3932160

// two-level grid barrier (16 groups x 16 blocks, monotonic)
DEVI void gridbar(int* bar, int& ep) {
  __syncthreads();
  if (threadIdx.x == 0) {
    __threadfence();
    int g = (int)(blockIdx.x & 15);
    int old = __hip_atomic_fetch_add(bar + g * 32, 1, __ATOMIC_RELAXED, __HIP_MEMORY_SCOPE_AGENT);
    if (old == ep * 16 - 1) {
      int o2 = __hip_atomic_fetch_add(bar + 512, 1, __ATOMIC_RELAXED, __HIP_MEMORY_SCOPE_AGENT);
      if (o2 == ep * 16 - 1)
        __hip_atomic_store(bar + 544, ep, __ATOMIC_RELAXED, __HIP_MEMORY_SCOPE_AGENT);
    }
    while (__hip_atomic_load(bar + 544, __ATOMIC_RELAXED, __HIP_MEMORY_SCOPE_AGENT) < ep)
      __builtin_amdgcn_s_sleep(1);
    __threadfence();
  }
  __syncthreads();
  ++ep;
}

__global__ void bar_init_kernel(int* bar) { bar[threadIdx.x] = 0; }

// B=64 TK=2048 TL=256 V=64 E=256 KV=128 H=512 MH=256
__global__ __launch_bounds__(1024, 4) void dec_kernel(KArgs A) {
  const int blk = blockIdx.x;
  const int tid = threadIdx.x;
  const int lane = tid & 63;
  const int w = tid >> 6;

  float* const LS   = A.ws + OF_LS;
  float* const Y0   = A.ws + OF_Y0;
  float* const XEMB = A.ws + OF_XEMB;
  float* const HSb  = A.ws + OF_HSB;
  float* const CSb  = A.ws + OF_CSB;
  float* const CTXP = A.ws + OF_CTXP;
  float* const MS   = A.ws + OF_MS;
  float* const QA   = A.ws + OF_QA;
  float* const WPACK= A.ws + OF_WPK;
  float* const WFCT = A.ws + OF_WFCT;
  int*   const bar  = (int*)(A.ws + OF_BAR);

  float* const out0 = A.out;              // y_hat [64][256][64]
  float* const out1 = A.out + 1048576;    // argmax as float [64][256]
  float* const out2 = A.out + 1064960;    // labels.T [64][256]
  float* const out3 = A.out + 1081344;    // labels_smoothed [64][256][64]
  float* const out4 = A.out + 2129920;    // attentions [64][2048][256]

  __shared__ __align__(16) float SMf[36992];   // 144.5 KB
  int ep = 1;

  u32 KA0, KA1, KB0, KB1;
  tf2x32(0u, 42u, 0u, 0u, KA0, KA1);
  tf2x32(0u, 42u, 0u, 1u, KB0, KB1);

  // ===== Prologue: pack weights (all blocks), then role work =====
  {
    for (int f = tid; f < 7168; f += 1024) {
      int r = f / 896, off = f - r * 896;
      int row = (r >> 1) * 512 + blk * 2 + (r & 1);
      float v = (off < 384) ? A.w_ih0[row * 384 + off] : A.w_hh0[row * 512 + off - 384];
      WPACK[blk * 7168 + f] = v;
    }
    for (int f = tid; f < 8192; f += 1024) {
      int r = f >> 10, off = f & 1023;
      int row = (r >> 1) * 512 + blk * 2 + (r & 1);
      WPACK[WP1 + blk * 8192 + f] = (off < 512) ? A.w_ih1[row * 512 + off] : A.w_hh1[row * 512 + off - 512];
    }
    for (int f = tid; f < 8192; f += 1024) {
      int r = f >> 10, off = f & 1023;
      int row = (r >> 1) * 512 + blk * 2 + (r & 1);
      WPACK[WP2 + blk * 8192 + f] = (off < 512) ? A.w_ih2[row * 512 + off] : A.w_hh2[row * 512 + off - 512];
    }
  }
  if (blk < 65) {
    int slot = blk * 1024 + tid;
    int r = slot >> 2, q = slot & 3;
    if (r < 16448) {
      bool isY0 = (r >= 16384);
      int t = 0, b, label;
      u32 key0, key1, base;
      if (!isY0) {
        t = r >> 6; b = r & 63;
        label = A.labels[t * 64 + b];
        key0 = KA0; key1 = KA1; base = (u32)(r * 64);
      } else {
        b = r - 16384;
        label = A.sos[0];
        key0 = KB0; key1 = KB1; base = (u32)(b * 64);
      }
      float sv[16];
      float mx = -3.0e38f;
      #pragma unroll
      for (int j = 0; j < 16; ++j) {
        int v = (q << 4) + j;
        float u = jax_uniform(key0, key1, base + (u32)v);
        float inner = -logf(u + 1e-10f) + 1e-10f;
        float noise = -logf(inner);
        float s = noise + ((v == label) ? 1.0f : 0.0f);
        sv[j] = s; mx = fmaxf(mx, s);
      }
      mx = fmaxf(mx, __shfl_xor(mx, 1));
      mx = fmaxf(mx, __shfl_xor(mx, 2));
      float sum = 0.f;
      #pragma unroll
      for (int j = 0; j < 16; ++j) { sv[j] = expf(sv[j] - mx); sum += sv[j]; }
      sum += __shfl_xor(sum, 1);
      sum += __shfl_xor(sum, 2);
      float inv = 1.0f / sum;
      if (!isY0) {
        #pragma unroll
        for (int j = 0; j < 16; ++j) {
          int v = (q << 4) + j;
          float val = sv[j] * inv;
          LS[r * 64 + v] = val;
          out3[b * 16384 + t * 64 + v] = val;
        }
        if (q == 0) out2[b * 256 + t] = (float)label;
      } else {
        #pragma unroll
        for (int j = 0; j < 16; ++j) Y0[b * 64 + (q << 4) + j] = sv[j] * inv;
      }
    }
  } else if (blk < 128) {
    // zero h/c (393216) + build WFCT (65536)
    const int total1 = 393216, total2 = 393216 + 65536;
    for (int idx = (blk - 65) * 1024 + tid; idx < total2; idx += 63 * 1024) {
      if (idx < total1) HSb[idx] = 0.f;
      else {
        int i2 = idx - total1;
        int kv = i2 >> 9, j = i2 & 511;
        WFCT[j * 128 + kv] = A.w_fc[kv * 512 + j];
      }
    }
  } else if (blk < 160) {
    int idx = (blk - 128) * 1024 + tid;     // 32768 = ctxp[0]
    CTXP[idx] = 0.f;
  } else if (blk == 160) {
    if (tid < 512) MS[tid] = ((tid >> 6) & 1) ? 1.0f : 0.0f;   // m=0, s=1
  }
  gridbar(bar, ep);

  // ===== Phase P1: embeddings XEMB[t] =====
  {
    const int t = blk;
    const float* src = (t == 0) ? Y0 : (LS + (t - 1) * 4096);
    #pragma unroll
    for (int i = 0; i < 4; ++i) {
      int idx = tid + i * 1024;
      SMf[(idx >> 6) * 65 + (idx & 63)] = src[idx];
    }
    __syncthreads();
    const int sl = tid >> 6, b = tid & 63;
    float* dst = XEMB + t * 16384;
    #pragma unroll 1
    for (int e0 = 0; e0 < 16; ++e0) {
      int e = sl * 16 + e0;
      const float* we = A.w_emb + e * 64;
      float acc = A.b_emb[e];
      #pragma unroll 8
      for (int v = 0; v < 64; ++v) acc = fmaf(we[v], SMf[b * 65 + v], acc);
      dst[e * 64 + b] = acc;
    }
  }
  gridbar(bar, ep);

  const int lenb = A.seqlens[blk >> 2];

  // ===== main recurrence: 4 barriers/step =====
  #pragma unroll 1
  for (int t = 0; t < 256; ++t) {
    const int p = t & 1;

    // ---- 3 LSTM layer phases ----
    #pragma unroll 1
    for (int l = 0; l < 3; ++l) {
      const int b = lane;
      float* WLp = SMf;                 // 8192
      float* XL0 = SMf + 8192;
      float* XL1 = SMf + 16384;
      float* CTXL = SMf + 24576;
      float* AL  = SMf + 32768;         // [4][64]
      const int KL = (l == 0) ? 896 : 1024;
      const int NT = (l == 0) ? 7 : 8;

      if (l == 0) {
        // combine ctx(t-1) partials -> CTXL [kv][b]
        if (tid < 64) {
          int b2 = tid;
          float m0 = MS[(t * 4 + 0) * 128 + b2], s0 = MS[(t * 4 + 0) * 128 + 64 + b2];
          float m1 = MS[(t * 4 + 1) * 128 + b2], s1 = MS[(t * 4 + 1) * 128 + 64 + b2];
          float m2 = MS[(t * 4 + 2) * 128 + b2], s2 = MS[(t * 4 + 2) * 128 + 64 + b2];
          float m3 = MS[(t * 4 + 3) * 128 + b2], s3 = MS[(t * 4 + 3) * 128 + 64 + b2];
          float m = fmaxf(fmaxf(m0, m1), fmaxf(m2, m3));
          float e0 = expf(m0 - m), e1 = expf(m1 - m), e2 = expf(m2 - m), e3 = expf(m3 - m);
          float iZ = 1.0f / (s0 * e0 + s1 * e1 + s2 * e2 + s3 * e3);
          AL[b2] = e0 * iZ; AL[64 + b2] = e1 * iZ; AL[128 + b2] = e2 * iZ; AL[192 + b2] = e3 * iZ;
        }
        __syncthreads();
        #pragma unroll
        for (int i2 = 0; i2 < 8; ++i2) {
          int idx = tid + i2 * 1024;
          int kv = idx >> 6, b2 = idx & 63;
          const float* cp = CTXP + (t * 4) * 8192 + kv * 64 + b2;
          CTXL[kv * 64 + b2] = cp[0] * AL[b2] + cp[8192] * AL[64 + b2]
                             + cp[16384] * AL[128 + b2] + cp[24576] * AL[192 + b2];
        }
        __syncthreads();
      }

      const float* wp = (l == 0) ? (WPACK + blk * 7168)
                      : (l == 1) ? (WPACK + WP1 + blk * 8192)
                                 : (WPACK + WP2 + blk * 8192);
      // x-tile source selector
      const float* hprev = HSb + (l * 2 + p) * 32768;
      const float* hin   = (l == 0) ? nullptr : (HSb + ((l - 1) * 2 + (p ^ 1)) * 32768);

      WAITV(0);
      {
        int NW = (l == 0) ? 28 : 32;
        for (int i = w; i < NW; i += 16) gl16(wp + i * 256 + lane * 4, WLp + i * 256);
        const float* xs0 = (l == 0) ? (XEMB + t * 16384) : hin;
        gl16(xs0 + (w * 2) * 256 + lane * 4, XL0 + (w * 2) * 256);
        gl16(xs0 + (w * 2 + 1) * 256 + lane * 4, XL0 + (w * 2 + 1) * 256);
      }
      WAITV(0);
      __syncthreads();

      float acc[8] = {0.f,0.f,0.f,0.f,0.f,0.f,0.f,0.f};
      #pragma unroll 1
      for (int tu = 0; tu < NT; ++tu) {
        int nxt = tu + 1;
        bool has = (nxt < NT) && !(l == 0 && nxt == 2);
        if (has) {
          const float* xsn;
          if (l == 0) xsn = (nxt < 2) ? (XEMB + t * 16384 + nxt * 8192) : (hprev + (nxt - 3) * 8192);
          else        xsn = (nxt < 4) ? (hin + nxt * 8192) : (hprev + (nxt - 4) * 8192);
          float* dstb = (nxt & 1) ? XL1 : XL0;
          gl16(xsn + (w * 2) * 256 + lane * 4, dstb + (w * 2) * 256);
          gl16(xsn + (w * 2 + 1) * 256 + lane * 4, dstb + (w * 2 + 1) * 256);
          WAITV(2);
        } else {
          WAITV(0);
        }
        __syncthreads();
        const float* XS = (l == 0 && tu == 2) ? CTXL : ((tu & 1) ? XL1 : XL0);
        float xv[8];
        #pragma unroll
        for (int j = 0; j < 8; ++j) xv[j] = XS[(w * 8 + j) * 64 + b];
        #pragma unroll
        for (int r = 0; r < 8; ++r) {
          const float* wr = &WLp[r * KL + tu * 128 + w * 8];
          float4 wa = *(const float4*)wr;
          float4 wb = *(const float4*)(wr + 4);
          acc[r] += wa.x * xv[0] + wa.y * xv[1] + wa.z * xv[2] + wa.w * xv[3]
                  + wb.x * xv[4] + wb.y * xv[5] + wb.z * xv[6] + wb.w * xv[7];
        }
        __syncthreads();
      }
      // reduce across 16 waves
      float* red = XL0;
      #pragma unroll
      for (int r = 0; r < 8; ++r) red[w * 512 + r * 64 + b] = acc[r];
      __syncthreads();
      if (tid < 128) {
        const float *bih, *bhh;
        if (l == 0)      { bih = A.b_ih0; bhh = A.b_hh0; }
        else if (l == 1) { bih = A.b_ih1; bhh = A.b_hh1; }
        else             { bih = A.b_ih2; bhh = A.b_hh2; }
        int jj = tid >> 6, bb = tid & 63;
        int j = blk * 2 + jj;
        float g4[4];
        #pragma unroll
        for (int g = 0; g < 4; ++g) {
          float s = 0.f;
          #pragma unroll
          for (int w2 = 0; w2 < 16; ++w2) s += red[w2 * 512 + (g * 2 + jj) * 64 + bb];
          int row = g * 512 + j;
          g4[g] = s + bih[row] + bhh[row];
        }
        float cprev = CSb[(l * 2 + p) * 32768 + j * 64 + bb];
        float c2 = sigmoidf_(g4[1]) * cprev + sigmoidf_(g4[0]) * tanhf(g4[2]);
        CSb[(l * 2 + (p ^ 1)) * 32768 + j * 64 + bb] = c2;
        HSb[(l * 2 + (p ^ 1)) * 32768 + j * 64 + bb] = sigmoidf_(g4[3]) * tanhf(c2);
      }
      gridbar(bar, ep);
    }

    // ---- ATTN phase: 4 blocks per b, chunk of 512 t ----
    {
      const int b = blk >> 2, ch = blk & 3, t0c = ch * 512;
      const float* H2 = HSb + (4 + (p ^ 1)) * 32768;
      float* qbuf  = SMf + 32768;   // 128
      float* h2col = SMf + 32896;   // 512
      float* pe    = SMf + 33408;   // 1024
      float* zs    = SMf + 34432;   // 512
      float* pc    = SMf + 34944;   // 1024
      float* mr    = SMf + 35968;   // 32

      // q = WFCT^T h2 + b_fc
      if (tid < 512) h2col[tid] = H2[tid * 64 + b];
      __syncthreads();
      {
        int jq = tid >> 7, kvq = tid & 127;
        const float* wf = WFCT + jq * 64 * 128 + kvq;
        float pa = 0.f;
        #pragma unroll 8
        for (int jl = 0; jl < 64; ++jl) pa = fmaf(wf[jl * 128], h2col[jq * 64 + jl], pa);
        pe[jq * 128 + kvq] = pa;
      }
      __syncthreads();
      if (tid < 128) {
        float qv = A.b_fc[tid];
        #pragma unroll
        for (int g = 0; g < 8; ++g) qv += pe[g * 128 + tid];
        qbuf[tid] = qv;
        if (ch == 0) QA[t * 8192 + tid * 64 + b] = qv;
      }
      __syncthreads();

      WAITV(0);
      // stage tile 0 (K, swizzled source)
      {
        const float* kb_g = A.enc_key + b * 262144 + (size_t)t0c * 128;
        #pragma unroll
        for (int s = 0; s < 4; ++s) {
          int i = w * 4 + s;
          int tloc = 2 * i + (lane >> 5);
          gl16(kb_g + tloc * 128 + (((lane & 31) ^ (tloc & 7)) << 2), SMf + i * 256);
        }
      }

      float ctxacc = 0.f;
      float m_sav = 0.f, s_sav = 0.f;
      #pragma unroll 1
      for (int tu = 0; tu < 8; ++tu) {
        if (tu < 7) {
          int tu1 = tu + 1;
          float* dst = SMf + ((tu1 & 1) ? 16384 : 0);
          if (tu1 < 4) {
            const float* kb_g = A.enc_key + b * 262144 + (size_t)(t0c + tu1 * 128) * 128;
            #pragma unroll
            for (int s = 0; s < 4; ++s) {
              int i = w * 4 + s;
              int tloc = 2 * i + (lane >> 5);
              gl16(kb_g + tloc * 128 + (((lane & 31) ^ (tloc & 7)) << 2), dst + i * 256);
            }
          } else {
            const float* vb_g = A.value + b * 262144 + (size_t)(t0c + (tu1 - 4) * 128) * 128;
            #pragma unroll
            for (int s = 0; s < 4; ++s) {
              int i = w * 4 + s;
              gl16(vb_g + (2 * i + (lane >> 5)) * 128 + ((lane & 31) << 2), dst + i * 256);
            }
          }
          WAITV(4);
        } else {
          WAITV(0);
        }
        __syncthreads();
        const float* BUF = SMf + ((tu & 1) ? 16384 : 0);
        if (tu < 4) {
          // energy partials
          int kq = tid >> 7, tl = tid & 127;
          const float* KB = BUF + tl * 128;
          int rot = tl & 7;
          float e = 0.f;
          #pragma unroll
          for (int gi = 0; gi < 4; ++gi) {
            int g = kq * 4 + gi;
            int slot = g ^ rot;
            float4 kv4 = *(const float4*)&KB[slot * 4];
            float4 q4  = *(const float4*)&qbuf[g * 4];
            e += kv4.x * q4.x + kv4.y * q4.y + kv4.z * q4.z + kv4.w * q4.w;
          }
          pe[kq * 128 + tl] = e;
          __syncthreads();
          if (tid < 128) {
            float ee = 0.f;
            #pragma unroll
            for (int g = 0; g < 8; ++g) ee += pe[g * 128 + tid];
            int ta = t0c + tu * 128 + tid;
            zs[tu * 128 + tid] = (ta < lenb) ? ee : 0.0f;   // energy * mask
          }
          if (tu == 3) {
            __syncthreads();
            float z = (tid < 512) ? zs[tid] : -3.0e38f;
            float mm = z;
            #pragma unroll
            for (int d = 1; d < 64; d <<= 1) mm = fmaxf(mm, __shfl_xor(mm, d));
            if (lane == 0 && w < 8) mr[w] = mm;
            __syncthreads();
            mm = mr[0];
            #pragma unroll
            for (int i2 = 1; i2 < 8; ++i2) mm = fmaxf(mm, mr[i2]);
            float ex = 0.f;
            if (tid < 512) { ex = expf(z - mm); zs[tid] = ex; }
            float ss = ex;
            #pragma unroll
            for (int d = 1; d < 64; d <<= 1) ss += __shfl_xor(ss, d);
            if (lane == 0 && w < 8) mr[8 + w] = ss;
            __syncthreads();
            float S = 0.f;
            #pragma unroll
            for (int i2 = 0; i2 < 8; ++i2) S += mr[8 + i2];
            m_sav = mm; s_sav = S;
          }
        } else {
          // ctx partial: pv += es[t] * V[t][kv]
          int tg = tid >> 7, kv = tid & 127;
          int tvb = (tu - 4) * 128;
          #pragma unroll 4
          for (int i2 = 0; i2 < 16; ++i2) {
            int tl2 = tg * 16 + i2;
            ctxacc = fmaf(zs[tvb + tl2], BUF[tl2 * 128 + kv], ctxacc);
          }
          __syncthreads();
        }
      }
      pc[tid] = ctxacc;
      __syncthreads();
      if (tid < 128) {
        float c = 0.f;
        #pragma unroll
        for (int g = 0; g < 8; ++g) c += pc[g * 128 + tid];
        CTXP[((t + 1) * 4 + ch) * 8192 + tid * 64 + b] = c;
      }
      if (tid < 512) out4[(size_t)b * 524288 + (size_t)(t0c + tid) * 256 + t] = zs[tid];
      if (tid == 0) {
        MS[((t + 1) * 4 + ch) * 128 + b] = m_sav;
        MS[((t + 1) * 4 + ch) * 128 + 64 + b] = s_sav;
      }
    }
    gridbar(bar, ep);
  }

  // ===== Epilogue: MLP head + argmax (block = t), then out4 normalize =====
  {
    const int t = blk;
    const int sl = tid >> 6, b = tid & 63;
    float* AL2 = SMf + 8512;    // [4][64]
    float acc1[16];
    #pragma unroll
    for (int i = 0; i < 16; ++i) acc1[i] = 0.f;
    #pragma unroll 1
    for (int h = 0; h < 2; ++h) {
      __syncthreads();
      if (h == 0) {
        const float* src = QA + t * 8192;
        #pragma unroll
        for (int i = 0; i < 8; ++i) {
          int idx = tid + i * 1024;
          SMf[(idx >> 6) * 65 + (idx & 63)] = src[idx];
        }
      } else {
        if (tid < 64) {
          int b2 = tid;
          float m0 = MS[((t+1)*4+0)*128 + b2], s0 = MS[((t+1)*4+0)*128 + 64 + b2];
          float m1 = MS[((t+1)*4+1)*128 + b2], s1 = MS[((t+1)*4+1)*128 + 64 + b2];
          float m2 = MS[((t+1)*4+2)*128 + b2], s2 = MS[((t+1)*4+2)*128 + 64 + b2];
          float m3 = MS[((t+1)*4+3)*128 + b2], s3 = MS[((t+1)*4+3)*128 + 64 + b2];
          float m = fmaxf(fmaxf(m0, m1), fmaxf(m2, m3));
          float e0 = expf(m0-m), e1 = expf(m1-m), e2 = expf(m2-m), e3 = expf(m3-m);
          float iZ = 1.0f / (s0*e0 + s1*e1 + s2*e2 + s3*e3);
          AL2[b2] = e0*iZ; AL2[64+b2] = e1*iZ; AL2[128+b2] = e2*iZ; AL2[192+b2] = e3*iZ;
        }
        __syncthreads();
        #pragma unroll
        for (int i = 0; i < 8; ++i) {
          int idx = tid + i * 1024;
          int kv = idx >> 6, b2 = idx & 63;
          const float* cp = CTXP + ((t + 1) * 4) * 8192 + kv * 64 + b2;
          SMf[kv * 65 + b2] = cp[0]*AL2[b2] + cp[8192]*AL2[64+b2]
                            + cp[16384]*AL2[128+b2] + cp[24576]*AL2[192+b2];
        }
      }
      __syncthreads();
      const float* w1 = A.w_mlp1 + (sl * 16) * 256 + h * 128;
      #pragma unroll 2
      for (int k = 0; k < 128; ++k) {
        float xv = SMf[k * 65 + b];
        #pragma unroll
        for (int m2 = 0; m2 < 16; ++m2) acc1[m2] = fmaf(w1[m2 * 256 + k], xv, acc1[m2]);
      }
    }
    #pragma unroll
    for (int m2 = 0; m2 < 16; ++m2) {
      float v2 = acc1[m2] + A.b_mlp1[sl * 16 + m2];
      acc1[m2] = (v2 >= 0.f) ? v2 : 0.9f * v2;
    }
    float y[4] = {0.f, 0.f, 0.f, 0.f};
    #pragma unroll 1
    for (int h = 0; h < 2; ++h) {
      __syncthreads();
      if ((sl >> 3) == h) {
        int base = (sl & 7) * 16;
        #pragma unroll
        for (int m2 = 0; m2 < 16; ++m2) SMf[(base + m2) * 65 + b] = acc1[m2];
      }
      __syncthreads();
      const float* w2 = A.w_mlp2 + (sl * 4) * 256 + h * 128;
      #pragma unroll 2
      for (int k = 0; k < 128; ++k) {
        float xv = SMf[k * 65 + b];
        #pragma unroll
        for (int m2 = 0; m2 < 4; ++m2) y[m2] = fmaf(w2[m2 * 256 + k], xv, y[m2]);
      }
    }
    #pragma unroll
    for (int m2 = 0; m2 < 4; ++m2) y[m2] += A.b_mlp2[sl * 4 + m2];
    *(float4*)(out0 + b * 16384 + t * 64 + sl * 4) = make_float4(y[0], y[1], y[2], y[3]);
    __syncthreads();
    #pragma unroll
    for (int m2 = 0; m2 < 4; ++m2) SMf[(sl * 4 + m2) * 65 + b] = y[m2];
    __syncthreads();
    if (tid < 64) {
      float best = SMf[tid];
      int bi = 0;
      #pragma unroll 1
      for (int v = 1; v < 64; ++v) {
        float val = SMf[v * 65 + tid];
        if (val > best) { best = val; bi = v; }
      }
      out1[tid * 256 + t] = (float)bi;
    }
  }
  // out4 normalization sweep: block handles (b, ch-quarter)
  __syncthreads();
  {
    const int b = blk >> 2, ch = blk & 3;
    float* at = SMf + 8768;   // [256]
    if (tid < 256) {
      int tl = tid;
      float mc[4], sc[4];
      #pragma unroll
      for (int c2 = 0; c2 < 4; ++c2) {
        mc[c2] = MS[((tl + 1) * 4 + c2) * 128 + b];
        sc[c2] = MS[((tl + 1) * 4 + c2) * 128 + 64 + b];
      }
      float m = fmaxf(fmaxf(mc[0], mc[1]), fmaxf(mc[2], mc[3]));
      float Z = sc[0]*expf(mc[0]-m) + sc[1]*expf(mc[1]-m) + sc[2]*expf(mc[2]-m) + sc[3]*expf(mc[3]-m);
      at[tl] = expf(mc[ch] - m) / Z;
    }
    __syncthreads();
    float* o4 = out4 + (size_t)b * 524288 + (size_t)ch * 512 * 256;
    #pragma unroll 2
    for (int i = 0; i < 32; ++i) {
      int idx = i * 1024 + tid;
      int tt = idx >> 6, c4 = (idx & 63) * 4;
      float4* p4 = (float4*)(o4 + tt * 256 + c4);
      float4 v = *p4;
      v.x *= at[c4]; v.y *= at[c4 + 1]; v.z *= at[c4 + 2]; v.w *= at[c4 + 3];
      *p4 = v;
    }
  }
}

extern "C" void kernel_launch(void* const* d_in, const int* in_sizes, int n_in,
                              void* d_out, int out_size, void* d_ws, size_t ws_size,
                              hipStream_t stream) {
  if (ws_size < (size_t)WS_TOTAL * 4) return;  // ~89.5 MB scratch
  KArgs a;
  a.enc_key = (const float*)d_in[0];
  a.value   = (const float*)d_in[1];
  a.labels  = (const int*)d_in[2];
  a.seqlens = (const int*)d_in[3];
  a.sos     = (const int*)d_in[4];
  a.w_emb  = (const float*)d_in[6];  a.b_emb  = (const float*)d_in[7];
  a.w_ih0  = (const float*)d_in[8];  a.w_hh0  = (const float*)d_in[9];
  a.b_ih0  = (const float*)d_in[10]; a.b_hh0  = (const float*)d_in[11];
  a.w_ih1  = (const float*)d_in[12]; a.w_hh1  = (const float*)d_in[13];
  a.b_ih1  = (const float*)d_in[14]; a.b_hh1  = (const float*)d_in[15];
  a.w_ih2  = (const float*)d_in[16]; a.w_hh2  = (const float*)d_in[17];
  a.b_ih2  = (const float*)d_in[18]; a.b_hh2  = (const float*)d_in[19];
  a.w_fc   = (const float*)d_in[20]; a.b_fc   = (const float*)d_in[21];
  a.w_mlp1 = (const float*)d_in[22]; a.b_mlp1 = (const float*)d_in[23];
  a.w_mlp2 = (const float*)d_in[24]; a.b_mlp2 = (const float*)d_in[25];
  a.out = (float*)d_out;
  a.ws  = (float*)d_ws;

  int* bar = (int*)((float*)d_ws + OF_BAR);
  hipLaunchKernelGGL(bar_init_kernel, dim3(1), dim3(1024), 0, stream, bar);

  void* args[] = { (void*)&a };
  hipLaunchCooperativeKernel(reinterpret_cast<void*>(dec_kernel),
                             dim3(256), dim3(1024), args, 0, stream);
}